// Round 2
// baseline (6995.921 us; speedup 1.0000x reference)
//
#include <hip/hip_runtime.h>

#define T_SZ 65536
#define K_SZ 2048
#define D_SZ 256

// numpy pairwise_sum replica for 128 contiguous squared elements.
// numpy: r[0..7] = a[0..7]; for i=8..120 step 8: r[j]+=a[i+j];
//        res = ((r0+r1)+(r2+r3))+((r4+r5)+(r6+r7))
// applied to a[i]^2 with each square rounded BEFORE the add (contract off).
__device__ __forceinline__ float pairwise128_sq(const float* __restrict__ a) {
#pragma clang fp contract(off)
  float r0 = a[0] * a[0], r1 = a[1] * a[1], r2 = a[2] * a[2], r3 = a[3] * a[3];
  float r4 = a[4] * a[4], r5 = a[5] * a[5], r6 = a[6] * a[6], r7 = a[7] * a[7];
#pragma unroll
  for (int i = 8; i < 128; i += 8) {
    r0 += a[i + 0] * a[i + 0];
    r1 += a[i + 1] * a[i + 1];
    r2 += a[i + 2] * a[i + 2];
    r3 += a[i + 3] * a[i + 3];
    r4 += a[i + 4] * a[i + 4];
    r5 += a[i + 5] * a[i + 5];
    r6 += a[i + 6] * a[i + 6];
    r7 += a[i + 7] * a[i + 7];
  }
  return ((r0 + r1) + (r2 + r3)) + ((r4 + r5) + (r6 + r7));
}

// e_sq[k] = numpy-pairwise sum of e[k][:]^2  (n=256 -> 128+128 split)
__global__ void esq_kernel(const float* __restrict__ e, float* __restrict__ esq) {
  int k = blockIdx.x * 64 + threadIdx.x;  // 32 blocks x 64 = 2048
  const float* er = e + (size_t)k * D_SZ;
  esq[k] = pairwise128_sq(er) + pairwise128_sq(er + 128);
}

// Main kernel: per block 128 rows x all 2048 codes (16 chunks of 128 codes).
// threads: tx = tid&15 (8 codes each), ty = tid>>4 (8 rows each).
// x comes global->register (broadcast across the 16 tx lanes, L1-resident slice);
// only the transposed e slice goes through LDS -> 2 ds_read_b128 per d-step,
// keeping the LDS pipe (~3.4k cyc/round/CU) under the FMA wall (~4.1k cyc).
__global__ __launch_bounds__(256, 2) void vq_argmin_kernel(
    const float* __restrict__ x, const float* __restrict__ e,
    const float* __restrict__ esq_g, float* __restrict__ outIdx) {
  // es: d-major e slice [buf][d(16)][code-slot 128]; slot layout: h-half major so
  //     dwords 4tx..4tx+3 hold codes 8tx..8tx+3 (h=0) and 64+4tx holds 8tx+4..7 (h=1).
  __shared__ __align__(16) float es[2][16][128];
  __shared__ float xsq_s[128];

  const int tid = threadIdx.x;
  const int tx = tid & 15;
  const int ty = tid >> 4;
  const int rowbase = blockIdx.x * 128;

  // --- x_sq for the block's 128 rows, numpy pairwise (threads 0..127, once) ---
  if (tid < 128) {
    const float* xr = x + (size_t)(rowbase + tid) * D_SZ;
    xsq_s[tid] = pairwise128_sq(xr) + pairwise128_sq(xr + 128);
  }

  const float4* x4 = reinterpret_cast<const float4*>(x);
  const float4* e4 = reinterpret_cast<const float4*>(e);

  float4 pe0, pe1;  // e prefetch registers (global -> reg -> transposed LDS)

  auto prefetch_e = [&](int round) {
    const int chunk = round >> 4, dstep = round & 15;
    const int code0 = tid >> 2, q = tid & 3;
    pe0 = e4[(size_t)(chunk * 128 + code0) * 64 + dstep * 4 + q];
    pe1 = e4[(size_t)(chunk * 128 + 64 + code0) * 64 + dstep * 4 + q];
  };

  auto write_es = [&](int buf) {
    const int q = tid & 3;
    const int code = tid >> 2;  // 0..63 (pe0), +64 (pe1)
    int slot0 = ((code >> 2) & 1) * 64 + (code >> 3) * 4 + (code & 3);
    es[buf][4 * q + 0][slot0] = pe0.x;
    es[buf][4 * q + 1][slot0] = pe0.y;
    es[buf][4 * q + 2][slot0] = pe0.z;
    es[buf][4 * q + 3][slot0] = pe0.w;
    const int code1 = 64 + code;
    int slot1 = ((code1 >> 2) & 1) * 64 + (code1 >> 3) * 4 + (code1 & 3);
    es[buf][4 * q + 0][slot1] = pe1.x;
    es[buf][4 * q + 1][slot1] = pe1.y;
    es[buf][4 * q + 2][slot1] = pe1.z;
    es[buf][4 * q + 3][slot1] = pe1.w;
  };

  prefetch_e(0);
  write_es(0);
  __syncthreads();

  float xsq[8];
#pragma unroll
  for (int r = 0; r < 8; ++r) xsq[r] = xsq_s[8 * ty + r];

  float acc[8][8];
#pragma unroll
  for (int r = 0; r < 8; ++r)
#pragma unroll
    for (int c = 0; c < 8; ++c) acc[r][c] = 0.0f;

  float bestv[8];
  int besti[8];
#pragma unroll
  for (int r = 0; r < 8; ++r) {
    bestv[r] = 3.402823466e38f;
    besti[r] = 0;
  }

  // This thread's 8 rows (8ty..8ty+7); row pitch = 64 float4s.
  const float4* xrow = x4 + (size_t)(rowbase + 8 * ty) * 64;

  // x register double-buffer: one 4-d group (8 rows x float4) per buffer.
  float4 xb[2][8];
#pragma unroll
  for (int i = 0; i < 8; ++i) xb[0][i] = xrow[i * 64 + 0];  // group 0

#pragma unroll 1
  for (int chunk = 0; chunk < 16; ++chunk) {
#pragma unroll 1
    for (int dstep = 0; dstep < 16; ++dstep) {
      const int round = chunk * 16 + dstep;
      const int buf = round & 1;
      if (round < 255) prefetch_e(round + 1);
#pragma unroll
      for (int sub = 0; sub < 4; ++sub) {
        const int g = dstep * 4 + sub;          // d-group within chunk, 0..63
        const int p = g & 1;
        const int gn = (g < 63) ? (g + 1) : 0;  // wraps to group 0 for next chunk
        // prefetch next 4-d group of x into the other buffer
#pragma unroll
        for (int i = 0; i < 8; ++i) xb[p ^ 1][i] = xrow[i * 64 + gn];
#pragma unroll
        for (int d = 0; d < 4; ++d) {
          const int dr = sub * 4 + d;  // d-row within this round's es slice
          float4 ev0 = *reinterpret_cast<const float4*>(&es[buf][dr][4 * tx]);
          float4 ev1 = *reinterpret_cast<const float4*>(&es[buf][dr][64 + 4 * tx]);
          float ec_[8] = {ev0.x, ev0.y, ev0.z, ev0.w, ev1.x, ev1.y, ev1.z, ev1.w};
#pragma unroll
          for (int r = 0; r < 8; ++r) {
            const float xv = (d == 0) ? xb[p][r].x
                           : (d == 1) ? xb[p][r].y
                           : (d == 2) ? xb[p][r].z
                                      : xb[p][r].w;
#pragma unroll
            for (int c = 0; c < 8; ++c)
              acc[r][c] = __builtin_fmaf(xv, ec_[c], acc[r][c]);
          }
        }
      }
      if (round < 255) write_es(buf ^ 1);
      __syncthreads();
    }
    // epilogue for this 128-code chunk: dist = (x_sq - 2*cross) + e_sq, running argmin
    const int nbase = chunk * 128;
#pragma unroll
    for (int c = 0; c < 8; ++c) {
      const int k = nbase + 8 * tx + c;  // ascending k within thread
      const float esq = esq_g[k];
#pragma unroll
      for (int r = 0; r < 8; ++r) {
        float t1 = xsq[r] - 2.0f * acc[r][c];  // 2*acc exact; sub matches np
        float dist = t1 + esq;
        bool better = dist < bestv[r];  // strict <: first (lowest k) wins ties
        bestv[r] = better ? dist : bestv[r];
        besti[r] = better ? k : besti[r];
        acc[r][c] = 0.0f;
      }
    }
  }

  // fold the 16 tx-lanes per row (lane bits 0..3 = tx); tie-break: lowest index
#pragma unroll
  for (int m = 1; m < 16; m <<= 1) {
#pragma unroll
    for (int r = 0; r < 8; ++r) {
      float ov = __shfl_xor(bestv[r], m, 64);
      int oi = __shfl_xor(besti[r], m, 64);
      bool take = (ov < bestv[r]) || ((ov == bestv[r]) && (oi < besti[r]));
      bestv[r] = take ? ov : bestv[r];
      besti[r] = take ? oi : besti[r];
    }
  }
  if (tx == 0) {
#pragma unroll
    for (int r = 0; r < 8; ++r)
      outIdx[rowbase + 8 * ty + r] = (float)besti[r];
  }
}

// out0 = x + (e[idx] - x), elementwise fp32 exactly as the reference
__global__ __launch_bounds__(256) void decode_kernel(
    const float* __restrict__ x, const float* __restrict__ e,
    const float* __restrict__ idxf, float* __restrict__ out) {
  size_t g = (size_t)blockIdx.x * 256 + threadIdx.x;  // float4 index
  size_t t = g >> 6;
  int q = (int)(g & 63);
  int idx = (int)idxf[t];  // wave-uniform
  const float4* x4 = reinterpret_cast<const float4*>(x);
  const float4* e4 = reinterpret_cast<const float4*>(e);
  float4 xv = x4[t * 64 + q];
  float4 qv = e4[(size_t)idx * 64 + q];
  float4 o;
  o.x = xv.x + (qv.x - xv.x);
  o.y = xv.y + (qv.y - xv.y);
  o.z = xv.z + (qv.z - xv.z);
  o.w = xv.w + (qv.w - xv.w);
  reinterpret_cast<float4*>(out)[g] = o;
}

extern "C" void kernel_launch(void* const* d_in, const int* in_sizes, int n_in,
                              void* d_out, int out_size, void* d_ws, size_t ws_size,
                              hipStream_t stream) {
  const float* x = (const float*)d_in[0];      // (65536, 256) fp32
  const float* e = (const float*)d_in[1];      // (2048, 256) fp32
  float* out = (float*)d_out;                  // [T*D quantized | T indices-as-float]
  float* esq = (float*)d_ws;                   // 2048 floats scratch
  float* outIdx = out + (size_t)T_SZ * D_SZ;

  esq_kernel<<<K_SZ / 64, 64, 0, stream>>>(e, esq);
  vq_argmin_kernel<<<T_SZ / 128, 256, 0, stream>>>(x, e, esq, outIdx);
  decode_kernel<<<(T_SZ * (D_SZ / 4)) / 256, 256, 0, stream>>>(x, e, outIdx, out);
}

// Round 3
// 1213.437 us; speedup vs baseline: 5.7654x; 5.7654x over previous
//
#include <hip/hip_runtime.h>

#define T_SZ 65536
#define K_SZ 2048
#define D_SZ 256

// numpy pairwise_sum replica for 128 contiguous squared elements.
// numpy: r[0..7] = a[0..7]; for i=8..120 step 8: r[j]+=a[i+j];
//        res = ((r0+r1)+(r2+r3))+((r4+r5)+(r6+r7))
// applied to a[i]^2 with each square rounded BEFORE the add (contract off).
__device__ __forceinline__ float pairwise128_sq(const float* __restrict__ a) {
#pragma clang fp contract(off)
  float r0 = a[0] * a[0], r1 = a[1] * a[1], r2 = a[2] * a[2], r3 = a[3] * a[3];
  float r4 = a[4] * a[4], r5 = a[5] * a[5], r6 = a[6] * a[6], r7 = a[7] * a[7];
#pragma unroll
  for (int i = 8; i < 128; i += 8) {
    r0 += a[i + 0] * a[i + 0];
    r1 += a[i + 1] * a[i + 1];
    r2 += a[i + 2] * a[i + 2];
    r3 += a[i + 3] * a[i + 3];
    r4 += a[i + 4] * a[i + 4];
    r5 += a[i + 5] * a[i + 5];
    r6 += a[i + 6] * a[i + 6];
    r7 += a[i + 7] * a[i + 7];
  }
  return ((r0 + r1) + (r2 + r3)) + ((r4 + r5) + (r6 + r7));
}

// e_sq[k] = numpy-pairwise sum of e[k][:]^2  (n=256 -> 128+128 split)
__global__ void esq_kernel(const float* __restrict__ e, float* __restrict__ esq) {
  int k = blockIdx.x * 64 + threadIdx.x;  // 32 blocks x 64 = 2048
  const float* er = e + (size_t)k * D_SZ;
  esq[k] = pairwise128_sq(er) + pairwise128_sq(er + 128);
}

// Main kernel: per block 128 rows x all 2048 codes (16 chunks of 128 codes).
// tx = tid&15 (codes k = 16c+tx, c=0..7), ty = tid>>4 (rows 8ty..8ty+7).
// x: global->register, broadcast across the 16 tx lanes (L1/L2-resident slice).
// e: staged through LDS, code-major [128][20 floats] (pitch 80B):
//   - writes: 2 x ds_write_b128/thread, bank = 4*((5*k0+q) mod 8)+w -> 8 dwords/bank,
//     conflict-free (no transpose needed).
//   - reads: lane tx reads code 16c+tx quad q: bank = 4*((5tx+q) mod 8)+w -> 2-way (free).
// VGPR budget (cap-aware after R1/R2 spill disasters): acc 64 + xg 32 + pe 8 +
// best 16 + transients ~25 ~= 145; launch_bounds(256,1) lifts the 128 cap.
__global__ __launch_bounds__(256, 1) void vq_argmin_kernel(
    const float* __restrict__ x, const float* __restrict__ e,
    const float* __restrict__ esq_g, float* __restrict__ outIdx) {
  __shared__ __align__(16) float es[2][128][20];
  __shared__ float xsq_s[128];

  const int tid = threadIdx.x;
  const int tx = tid & 15;
  const int ty = tid >> 4;
  const int rowbase = blockIdx.x * 128;

  // --- x_sq for the block's 128 rows, numpy pairwise (threads 0..127, once) ---
  if (tid < 128) {
    const float* xr = x + (size_t)(rowbase + tid) * D_SZ;
    xsq_s[tid] = pairwise128_sq(xr) + pairwise128_sq(xr + 128);
  }

  const float4* x4 = reinterpret_cast<const float4*>(x);
  const float4* e4 = reinterpret_cast<const float4*>(e);

  const int k0 = tid >> 2;  // staging code (0..63; +64 for second)
  const int q0 = tid & 3;   // staging quad

  float4 pe0, pe1;  // e prefetch registers (global -> reg -> LDS, no transpose)

  auto prefetch_e = [&](int round) {
    const int chunk = round >> 4, dstep = round & 15;
    pe0 = e4[(size_t)(chunk * 128 + k0) * 64 + dstep * 4 + q0];
    pe1 = e4[(size_t)(chunk * 128 + 64 + k0) * 64 + dstep * 4 + q0];
  };

  auto write_es = [&](int buf) {
    *reinterpret_cast<float4*>(&es[buf][k0][4 * q0]) = pe0;
    *reinterpret_cast<float4*>(&es[buf][64 + k0][4 * q0]) = pe1;
  };

  prefetch_e(0);
  write_es(0);
  __syncthreads();

  float acc[8][8];
#pragma unroll
  for (int r = 0; r < 8; ++r)
#pragma unroll
    for (int c = 0; c < 8; ++c) acc[r][c] = 0.0f;

  float bestv[8];
  int besti[8];
#pragma unroll
  for (int r = 0; r < 8; ++r) {
    bestv[r] = 3.402823466e38f;
    besti[r] = 0;
  }

  // This thread's 8 rows (8ty..8ty+7); row pitch = 64 float4s.
  const float4* xrow = x4 + (size_t)(rowbase + 8 * ty) * 64;

#pragma unroll 1
  for (int chunk = 0; chunk < 16; ++chunk) {
#pragma unroll 1
    for (int dstep = 0; dstep < 16; ++dstep) {
      const int round = chunk * 16 + dstep;
      const int buf = round & 1;
      if (round < 255) prefetch_e(round + 1);
#pragma unroll 1
      for (int q = 0; q < 4; ++q) {
        // load this 4-d group of x (8 rows), broadcast across tx lanes
        float4 xg[8];
#pragma unroll
        for (int i = 0; i < 8; ++i) xg[i] = xrow[i * 64 + dstep * 4 + q];
#pragma unroll
        for (int c = 0; c < 8; ++c) {
          float4 ev = *reinterpret_cast<const float4*>(&es[buf][16 * c + tx][4 * q]);
#pragma unroll
          for (int r = 0; r < 8; ++r) {
            // d ascending within the quad -> global d order 0..255 sequential
            acc[r][c] = __builtin_fmaf(xg[r].x, ev.x, acc[r][c]);
            acc[r][c] = __builtin_fmaf(xg[r].y, ev.y, acc[r][c]);
            acc[r][c] = __builtin_fmaf(xg[r].z, ev.z, acc[r][c]);
            acc[r][c] = __builtin_fmaf(xg[r].w, ev.w, acc[r][c]);
          }
        }
      }
      if (round < 255) write_es(buf ^ 1);
      __syncthreads();
    }
    // epilogue for this 128-code chunk: dist = (x_sq - 2*cross) + e_sq, running argmin
    const int nbase = chunk * 128;
#pragma unroll
    for (int c = 0; c < 8; ++c) {
      const int k = nbase + 16 * c + tx;  // ascending k within thread
      const float esq = esq_g[k];
#pragma unroll
      for (int r = 0; r < 8; ++r) {
        float xsq = xsq_s[8 * ty + r];          // broadcast LDS read (free)
        float t1 = xsq - 2.0f * acc[r][c];      // 2*acc exact; matches np
        float dist = t1 + esq;
        bool better = dist < bestv[r];  // strict <: first (lowest k) wins ties
        bestv[r] = better ? dist : bestv[r];
        besti[r] = better ? k : besti[r];
        acc[r][c] = 0.0f;
      }
    }
  }

  // fold the 16 tx-lanes per row (lane bits 0..3 = tx); tie-break: lowest index
#pragma unroll
  for (int m = 1; m < 16; m <<= 1) {
#pragma unroll
    for (int r = 0; r < 8; ++r) {
      float ov = __shfl_xor(bestv[r], m, 64);
      int oi = __shfl_xor(besti[r], m, 64);
      bool take = (ov < bestv[r]) || ((ov == bestv[r]) && (oi < besti[r]));
      bestv[r] = take ? ov : bestv[r];
      besti[r] = take ? oi : besti[r];
    }
  }
  if (tx == 0) {
#pragma unroll
    for (int r = 0; r < 8; ++r)
      outIdx[rowbase + 8 * ty + r] = (float)besti[r];
  }
}

// out0 = x + (e[idx] - x), elementwise fp32 exactly as the reference
__global__ __launch_bounds__(256) void decode_kernel(
    const float* __restrict__ x, const float* __restrict__ e,
    const float* __restrict__ idxf, float* __restrict__ out) {
  size_t g = (size_t)blockIdx.x * 256 + threadIdx.x;  // float4 index
  size_t t = g >> 6;
  int q = (int)(g & 63);
  int idx = (int)idxf[t];  // wave-uniform
  const float4* x4 = reinterpret_cast<const float4*>(x);
  const float4* e4 = reinterpret_cast<const float4*>(e);
  float4 xv = x4[t * 64 + q];
  float4 qv = e4[(size_t)idx * 64 + q];
  float4 o;
  o.x = xv.x + (qv.x - xv.x);
  o.y = xv.y + (qv.y - xv.y);
  o.z = xv.z + (qv.z - xv.z);
  o.w = xv.w + (qv.w - xv.w);
  reinterpret_cast<float4*>(out)[g] = o;
}

extern "C" void kernel_launch(void* const* d_in, const int* in_sizes, int n_in,
                              void* d_out, int out_size, void* d_ws, size_t ws_size,
                              hipStream_t stream) {
  const float* x = (const float*)d_in[0];      // (65536, 256) fp32
  const float* e = (const float*)d_in[1];      // (2048, 256) fp32
  float* out = (float*)d_out;                  // [T*D quantized | T indices-as-float]
  float* esq = (float*)d_ws;                   // 2048 floats scratch
  float* outIdx = out + (size_t)T_SZ * D_SZ;

  esq_kernel<<<K_SZ / 64, 64, 0, stream>>>(e, esq);
  vq_argmin_kernel<<<T_SZ / 128, 256, 0, stream>>>(x, e, esq, outIdx);
  decode_kernel<<<(T_SZ * (D_SZ / 4)) / 256, 256, 0, stream>>>(x, e, outIdx, out);
}

// Round 4
// 1184.966 us; speedup vs baseline: 5.9039x; 1.0240x over previous
//
#include <hip/hip_runtime.h>

#define T_SZ 65536
#define K_SZ 2048
#define D_SZ 256

// numpy pairwise_sum replica for 128 contiguous squared elements.
// numpy: r[0..7] = a[0..7]; for i=8..120 step 8: r[j]+=a[i+j];
//        res = ((r0+r1)+(r2+r3))+((r4+r5)+(r6+r7))
// applied to a[i]^2 with each square rounded BEFORE the add (contract off).
__device__ __forceinline__ float pairwise128_sq(const float* __restrict__ a) {
#pragma clang fp contract(off)
  float r0 = a[0] * a[0], r1 = a[1] * a[1], r2 = a[2] * a[2], r3 = a[3] * a[3];
  float r4 = a[4] * a[4], r5 = a[5] * a[5], r6 = a[6] * a[6], r7 = a[7] * a[7];
#pragma unroll
  for (int i = 8; i < 128; i += 8) {
    r0 += a[i + 0] * a[i + 0];
    r1 += a[i + 1] * a[i + 1];
    r2 += a[i + 2] * a[i + 2];
    r3 += a[i + 3] * a[i + 3];
    r4 += a[i + 4] * a[i + 4];
    r5 += a[i + 5] * a[i + 5];
    r6 += a[i + 6] * a[i + 6];
    r7 += a[i + 7] * a[i + 7];
  }
  return ((r0 + r1) + (r2 + r3)) + ((r4 + r5) + (r6 + r7));
}

// e_sq[k] = numpy-pairwise sum of e[k][:]^2  (n=256 -> 128+128 split)
__global__ void esq_kernel(const float* __restrict__ e, float* __restrict__ esq) {
  int k = blockIdx.x * 64 + threadIdx.x;  // 32 blocks x 64 = 2048
  const float* er = e + (size_t)k * D_SZ;
  esq[k] = pairwise128_sq(er) + pairwise128_sq(er + 128);
}

// Main kernel: per block 128 rows x 1024 codes (half the codebook, 8 chunks of 128).
// K is split across 2 blocks per row-tile (half = blockIdx.x & 1) purely for
// occupancy: grid 1024 -> 4 blocks/CU = 4 waves/SIMD (R3 was 2 blocks/CU and
// latency-bound at VALUBusy 53%). Per-wave LDS:FMA ratio is split-invariant.
// tx = tid&15 (codes k = kbase+128*chunk+16c+tx), ty = tid>>4 (rows 8ty..8ty+7).
// x: global->register, broadcast across the 16 tx lanes (L1/L2-resident slice).
// e: staged through LDS, code-major [128][20 floats] (pitch 80B):
//   - writes: 2 x ds_write_b128/thread, conflict-free; reads 2-way (free).
// VGPR budget: acc 64 + xg 32 + pe 8 + best 16 + transients ~25 ~= 145 demand,
// allocator lands at 80; launch_bounds(256,1) avoids the 128-cap spill disaster.
__global__ __launch_bounds__(256, 1) void vq_argmin_kernel(
    const float* __restrict__ x, const float* __restrict__ e,
    const float* __restrict__ esq_g, float* __restrict__ cand_v,
    int* __restrict__ cand_i) {
  __shared__ __align__(16) float es[2][128][20];
  __shared__ float xsq_s[128];

  const int tid = threadIdx.x;
  const int tx = tid & 15;
  const int ty = tid >> 4;
  const int half = blockIdx.x & 1;
  const int rowbase = (blockIdx.x >> 1) * 128;
  const int kbase = half * 1024;

  // --- x_sq for the block's 128 rows, numpy pairwise (threads 0..127, once) ---
  if (tid < 128) {
    const float* xr = x + (size_t)(rowbase + tid) * D_SZ;
    xsq_s[tid] = pairwise128_sq(xr) + pairwise128_sq(xr + 128);
  }

  const float4* x4 = reinterpret_cast<const float4*>(x);
  const float4* e4 = reinterpret_cast<const float4*>(e);

  const int k0 = tid >> 2;  // staging code (0..63; +64 for second)
  const int q0 = tid & 3;   // staging quad

  float4 pe0, pe1;  // e prefetch registers (global -> reg -> LDS, no transpose)

  auto prefetch_e = [&](int round) {
    const int chunk = round >> 4, dstep = round & 15;
    pe0 = e4[(size_t)(kbase + chunk * 128 + k0) * 64 + dstep * 4 + q0];
    pe1 = e4[(size_t)(kbase + chunk * 128 + 64 + k0) * 64 + dstep * 4 + q0];
  };

  auto write_es = [&](int buf) {
    *reinterpret_cast<float4*>(&es[buf][k0][4 * q0]) = pe0;
    *reinterpret_cast<float4*>(&es[buf][64 + k0][4 * q0]) = pe1;
  };

  prefetch_e(0);
  write_es(0);
  __syncthreads();

  float acc[8][8];
#pragma unroll
  for (int r = 0; r < 8; ++r)
#pragma unroll
    for (int c = 0; c < 8; ++c) acc[r][c] = 0.0f;

  float bestv[8];
  int besti[8];
#pragma unroll
  for (int r = 0; r < 8; ++r) {
    bestv[r] = 3.402823466e38f;
    besti[r] = 0;
  }

  // This thread's 8 rows (8ty..8ty+7); row pitch = 64 float4s.
  const float4* xrow = x4 + (size_t)(rowbase + 8 * ty) * 64;

#pragma unroll 1
  for (int chunk = 0; chunk < 8; ++chunk) {
#pragma unroll 1
    for (int dstep = 0; dstep < 16; ++dstep) {
      const int round = chunk * 16 + dstep;
      const int buf = round & 1;
      if (round < 127) prefetch_e(round + 1);
#pragma unroll 1
      for (int q = 0; q < 4; ++q) {
        // load this 4-d group of x (8 rows), broadcast across tx lanes
        float4 xg[8];
#pragma unroll
        for (int i = 0; i < 8; ++i) xg[i] = xrow[i * 64 + dstep * 4 + q];
#pragma unroll
        for (int c = 0; c < 8; ++c) {
          float4 ev = *reinterpret_cast<const float4*>(&es[buf][16 * c + tx][4 * q]);
#pragma unroll
          for (int r = 0; r < 8; ++r) {
            // d ascending within the quad -> global d order 0..255 sequential
            acc[r][c] = __builtin_fmaf(xg[r].x, ev.x, acc[r][c]);
            acc[r][c] = __builtin_fmaf(xg[r].y, ev.y, acc[r][c]);
            acc[r][c] = __builtin_fmaf(xg[r].z, ev.z, acc[r][c]);
            acc[r][c] = __builtin_fmaf(xg[r].w, ev.w, acc[r][c]);
          }
        }
      }
      if (round < 127) write_es(buf ^ 1);
      __syncthreads();
    }
    // epilogue for this 128-code chunk: dist = (x_sq - 2*cross) + e_sq, running argmin
    const int nbase = kbase + chunk * 128;
#pragma unroll
    for (int c = 0; c < 8; ++c) {
      const int k = nbase + 16 * c + tx;  // ascending k within thread
      const float esq = esq_g[k];
#pragma unroll
      for (int r = 0; r < 8; ++r) {
        float xsq = xsq_s[8 * ty + r];          // broadcast LDS read (free)
        float t1 = xsq - 2.0f * acc[r][c];      // 2*acc exact; matches np
        float dist = t1 + esq;
        bool better = dist < bestv[r];  // strict <: first (lowest k) wins ties
        bestv[r] = better ? dist : bestv[r];
        besti[r] = better ? k : besti[r];
        acc[r][c] = 0.0f;
      }
    }
  }

  // fold the 16 tx-lanes per row (lane bits 0..3 = tx); tie-break: lowest index
#pragma unroll
  for (int m = 1; m < 16; m <<= 1) {
#pragma unroll
    for (int r = 0; r < 8; ++r) {
      float ov = __shfl_xor(bestv[r], m, 64);
      int oi = __shfl_xor(besti[r], m, 64);
      bool take = (ov < bestv[r]) || ((ov == bestv[r]) && (oi < besti[r]));
      bestv[r] = take ? ov : bestv[r];
      besti[r] = take ? oi : besti[r];
    }
  }
  if (tx == 0) {
#pragma unroll
    for (int r = 0; r < 8; ++r) {
      cand_v[half * T_SZ + rowbase + 8 * ty + r] = bestv[r];
      cand_i[half * T_SZ + rowbase + 8 * ty + r] = besti[r];
    }
  }
}

// Combine the two K-halves (strict < : half 0 wins ties -> lower index, matching
// np.argmin first-occurrence), then out0 = x + (e[idx] - x) elementwise fp32.
__global__ __launch_bounds__(256) void decode_kernel(
    const float* __restrict__ x, const float* __restrict__ e,
    const float* __restrict__ cand_v, const int* __restrict__ cand_i,
    float* __restrict__ out, float* __restrict__ outIdx) {
  size_t g = (size_t)blockIdx.x * 256 + threadIdx.x;  // float4 index
  size_t t = g >> 6;
  int q = (int)(g & 63);
  float v0 = cand_v[t], v1 = cand_v[T_SZ + t];
  int i0 = cand_i[t], i1 = cand_i[T_SZ + t];
  int idx = (v1 < v0) ? i1 : i0;  // wave-uniform (t uniform across the wave)
  if (q == 0) outIdx[t] = (float)idx;
  const float4* x4 = reinterpret_cast<const float4*>(x);
  const float4* e4 = reinterpret_cast<const float4*>(e);
  float4 xv = x4[t * 64 + q];
  float4 qv = e4[(size_t)idx * 64 + q];
  float4 o;
  o.x = xv.x + (qv.x - xv.x);
  o.y = xv.y + (qv.y - xv.y);
  o.z = xv.z + (qv.z - xv.z);
  o.w = xv.w + (qv.w - xv.w);
  reinterpret_cast<float4*>(out)[g] = o;
}

extern "C" void kernel_launch(void* const* d_in, const int* in_sizes, int n_in,
                              void* d_out, int out_size, void* d_ws, size_t ws_size,
                              hipStream_t stream) {
  const float* x = (const float*)d_in[0];      // (65536, 256) fp32
  const float* e = (const float*)d_in[1];      // (2048, 256) fp32
  float* out = (float*)d_out;                  // [T*D quantized | T indices-as-float]
  float* outIdx = out + (size_t)T_SZ * D_SZ;

  float* esq = (float*)d_ws;                       // 2048 floats
  float* cand_v = esq + K_SZ;                      // 2*T floats
  int* cand_i = (int*)(cand_v + 2 * T_SZ);         // 2*T ints

  esq_kernel<<<K_SZ / 64, 64, 0, stream>>>(e, esq);
  vq_argmin_kernel<<<(T_SZ / 128) * 2, 256, 0, stream>>>(x, e, esq, cand_v, cand_i);
  decode_kernel<<<(T_SZ * (D_SZ / 4)) / 256, 256, 0, stream>>>(x, e, cand_v, cand_i,
                                                               out, outIdx);
}